// Round 3
// baseline (219.329 us; speedup 1.0000x reference)
//
#include <hip/hip_runtime.h>
#include <stdint.h>
#include <stddef.h>

// Problem constants
#define B_ 4
#define L_ 8192
#define D_ 512
#define M_ (B_*L_)      // 32768 rows
#define K_ 512
#define CHUNK 64
#define NC (L_/CHUNK)   // 128 chunks per sequence

typedef _Float16 f16;
typedef f16 f16x2 __attribute__((ext_vector_type(2)));
typedef f16 f16x4 __attribute__((ext_vector_type(4)));
typedef f16 f16x8 __attribute__((ext_vector_type(8)));
typedef float f32x4 __attribute__((ext_vector_type(4)));

// ---------------- async global->LDS (16B/lane) ----------------
__device__ __forceinline__ void async16(const void* g, void* l) {
  __builtin_amdgcn_global_load_lds(
      (const __attribute__((address_space(1))) uint32_t*)g,
      (__attribute__((address_space(3))) uint32_t*)l,
      16, 0, 0);
}

// ---------------- prep: pack Wg ++ Wc into f16 [1024][512] ----------------
__global__ __launch_bounds__(256) void prep_w(const float* __restrict__ Wg,
                                              const float* __restrict__ Wc,
                                              f16* __restrict__ wp) {
  const int idx = (blockIdx.x * 256 + threadIdx.x) * 4;  // 0..524287
  const float* src = (idx < 262144) ? (Wg + idx) : (Wc + (idx - 262144));
  float4 v = *(const float4*)src;
  f16x4 o = {(f16)v.x, (f16)v.y, (f16)v.z, (f16)v.w};
  *(f16x4*)(wp + idx) = o;
}

// ---------------- fused dual-B GEMM + activations + chunk composites ------
// v3: T3 minimum-2-phase schedule. ONE raw s_barrier per K-step, counted
// vmcnt(4) (A-reg loads for t+2 stay in flight across the barrier), no
// sched_barrier pinning, compiler inserts all fine-grained lgkm waits for
// the ds_read->MFMA path. A is reg-staged from fp32 x (fused cvt).
__global__ __launch_bounds__(256, 2) void gemm_act(
    const float* __restrict__ X, const f16* __restrict__ Wp,
    const float* __restrict__ bg, const float* __restrict__ bc,
    uint32_t* __restrict__ AC,
    float* __restrict__ cA, float* __restrict__ cB) {
  __shared__ __align__(16) f16 sA[2][128 * 32];
  __shared__ __align__(16) f16 sBg[2][128 * 32];
  __shared__ __align__(16) f16 sBc[2][128 * 32];

  const int tid = threadIdx.x;
  // XCD swizzle: same bm-tile's 4 col-blocks run consecutively on one XCD
  const int id = blockIdx.x;           // 0..1023
  const int xcd = id & 7;
  const int slot = id >> 3;            // 0..127
  const int g_ = xcd * 128 + slot;
  const int bm = g_ >> 2;              // 0..255
  const int bn = g_ & 3;               // 0..3 (128-col tiles)

  const int lane = tid & 63;
  const int w = tid >> 6;
  const int wm = w >> 1, wn = w & 1;   // 2x2 wave grid over 128x128
  const int l15 = lane & 15, quad = lane >> 4;

  // staging: tid -> (row = tid>>2, 8-elem piece = tid&3); covers 64 rows/round
  const int srow = tid >> 2;
  const int spc8 = (tid & 3) * 8;
  const float* gx = X + (size_t)(bm * 128 + srow) * K_ + spc8;       // fp32!
  const f16* gBg = Wp + (size_t)(bn * 128 + srow) * K_ + spc8;
  const f16* gBc = Wp + (size_t)(512 + bn * 128 + srow) * K_ + spc8;

  f32x4 accG[4][4] = {};
  f32x4 accC[4][4] = {};

  float4 ax0, ax1, ax2, ax3;           // A staging registers (1 tile deep)

#define ISSUE_A(kk) { \
    ax0 = *(const float4*)(gx + (kk)); \
    ax1 = *(const float4*)(gx + (kk) + 4); \
    ax2 = *(const float4*)(gx + 64 * K_ + (kk)); \
    ax3 = *(const float4*)(gx + 64 * K_ + (kk) + 4); }

#define STAGE_B(kk, bN) { \
    async16(gBg + (kk), &sBg[bN][tid * 8]); \
    async16(gBg + 64 * K_ + (kk), &sBg[bN][tid * 8 + 64 * 32]); \
    async16(gBc + (kk), &sBc[bN][tid * 8]); \
    async16(gBc + 64 * K_ + (kk), &sBc[bN][tid * 8 + 64 * 32]); }

#define WRITE_A(bN) { \
    f16x8 w0 = {(f16)ax0.x, (f16)ax0.y, (f16)ax0.z, (f16)ax0.w, \
                (f16)ax1.x, (f16)ax1.y, (f16)ax1.z, (f16)ax1.w}; \
    f16x8 w1 = {(f16)ax2.x, (f16)ax2.y, (f16)ax2.z, (f16)ax2.w, \
                (f16)ax3.x, (f16)ax3.y, (f16)ax3.z, (f16)ax3.w}; \
    *(f16x8*)&sA[bN][tid * 8] = w0; \
    *(f16x8*)&sA[bN][tid * 8 + 64 * 32] = w1; }

#define COMPUTE(bC) { \
    f16x8 af[4], bgf[4], bcf[4]; \
    _Pragma("unroll") \
    for (int i = 0; i < 4; i++) \
      af[i] = *(const f16x8*)(&sA[bC][(wm * 64 + i * 16 + l15) * 32 + quad * 8]); \
    _Pragma("unroll") \
    for (int j = 0; j < 4; j++) { \
      bgf[j] = *(const f16x8*)(&sBg[bC][(wn * 64 + j * 16 + l15) * 32 + quad * 8]); \
      bcf[j] = *(const f16x8*)(&sBc[bC][(wn * 64 + j * 16 + l15) * 32 + quad * 8]); \
    } \
    _Pragma("unroll") \
    for (int i = 0; i < 4; i++) \
      _Pragma("unroll") \
      for (int j = 0; j < 4; j++) { \
        accG[i][j] = __builtin_amdgcn_mfma_f32_16x16x32_f16(af[i], bgf[j], accG[i][j], 0, 0, 0); \
        accC[i][j] = __builtin_amdgcn_mfma_f32_16x16x32_f16(af[i], bcf[j], accC[i][j], 0, 0, 0); \
      } }

  // Prologue: stage tile0 into buf0; preload A regs for tile1.
  ISSUE_A(0);
  STAGE_B(0, 0);
  WRITE_A(0);                          // compiler auto-waits ax(tile0)
  asm volatile("" ::: "memory");       // keep B(0) issue older than ax(tile1)
  ISSUE_A(32);
  asm volatile("s_waitcnt vmcnt(4) lgkmcnt(0)" ::: "memory");  // B(0)+A writes done
  __builtin_amdgcn_s_barrier();

  // Per-iter: stage t+1 into n, compute t from c, keep ax(t+2) in flight.
#define BODY(kt, bC, bN, DO_ISSUE) { \
    STAGE_B(((kt) + 1) * 32, bN); \
    WRITE_A(bN); \
    asm volatile("" ::: "memory"); \
    if (DO_ISSUE) { ISSUE_A(((kt) + 2) * 32); } \
    COMPUTE(bC); \
    if (DO_ISSUE) { asm volatile("s_waitcnt vmcnt(4) lgkmcnt(0)" ::: "memory"); } \
    else          { asm volatile("s_waitcnt vmcnt(0) lgkmcnt(0)" ::: "memory"); } \
    __builtin_amdgcn_s_barrier(); }

  for (int t2 = 0; t2 < 7; t2++) {
    BODY(t2 * 2,     0, 1, 1);
    BODY(t2 * 2 + 1, 1, 0, 1);
  }
  BODY(14, 0, 1, 0);                   // stages tile15, no new A issue
  COMPUTE(1);                          // tile 15, no trailing barrier
#undef BODY
#undef COMPUTE
#undef WRITE_A
#undef STAGE_B
#undef ISSUE_A

  // Epilogue: sigmoid/tanh, pack (a,b) f16x2 -> AC, and per-chunk (P,Q).
  // Wave (wm) owns rows [wm*64, wm*64+64) = exactly chunk c.
  // Within chunk, time index t = i*16 + quad*4 + r (lexicographic i,quad,r).
  const int c = bm * 2 + wm;           // global chunk index 0..511
#pragma unroll
  for (int j = 0; j < 4; j++) {
    const int col = bn * 128 + wn * 64 + j * 16 + l15;   // 0..511
    const float bgv = bg[col];
    const float bcv = bc[col];
    float blkP[4], blkQ[4];
#pragma unroll
    for (int i = 0; i < 4; i++) {
      const int mrow = bm * 128 + wm * 64 + i * 16 + quad * 4;
      float P = 1.0f, Q = 0.0f;
#pragma unroll
      for (int r = 0; r < 4; r++) {
        float yg = accG[i][j][r] + bgv;
        float gg = 1.0f / (1.0f + __expf(-yg));        // sigmoid
        float yc = accC[i][j][r] + bcv;
        yc = fminf(fmaxf(yc, -15.0f), 15.0f);
        float t = __expf(2.0f * yc);
        float cc = (t - 1.0f) / (t + 1.0f);            // tanh
        f16x2 p;
        p[0] = (f16)(1.0f - gg);                        // a
        p[1] = (f16)(gg * cc);                          // b
        *(f16x2*)&AC[(size_t)(mrow + r) * 512 + col] = p;
        // compose with the SAME f16-rounded values scan_apply will read
        const float av = (float)p[0];
        const float bv = (float)p[1];
        Q = fmaf(av, Q, bv);                            // seg over r (t asc)
        P *= av;
      }
      // ordered cross-quad compose: quads 0..3 are consecutive t-segments.
      // comp(first,second) = (Ps*Pf, Ps*Qf + Qs)
      float Pp = __shfl_xor(P, 16);
      float Qp = __shfl_xor(Q, 16);
      float nP = P * Pp;
      float nQ = (quad & 1) ? fmaf(P, Qp, Q) : fmaf(Pp, Q, Qp);
      Pp = __shfl_xor(nP, 32);
      Qp = __shfl_xor(nQ, 32);
      blkP[i] = nP * Pp;
      blkQ[i] = (quad & 2) ? fmaf(nP, Qp, nQ) : fmaf(Pp, nQ, Qp);
    }
    // compose the 4 sixteen-row blocks in t order
    float CP = blkP[0], CQ = blkQ[0];
#pragma unroll
    for (int i = 1; i < 4; i++) {
      CQ = fmaf(blkP[i], CQ, blkQ[i]);
      CP *= blkP[i];
    }
    if (quad == 0) {
      cA[(size_t)c * 512 + col] = CP;
      cB[(size_t)c * 512 + col] = CQ;
    }
  }
}

// ---------------- scan pass 2: prefix over chunks -> Hpre ----------------
// 2048 independent (b,d) chains, 128 steps each; removes the O(ch) serial
// prefix redo that scan_apply blocks were paying per-block.
__global__ __launch_bounds__(64) void scan_chunks(
    const float* __restrict__ cA, const float* __restrict__ cB,
    float* __restrict__ Hpre) {
  const int b = blockIdx.x >> 3;
  const int d = ((blockIdx.x & 7) << 6) + threadIdx.x;
  float h = 0.0f;
#pragma unroll 8
  for (int ch = 0; ch < NC; ch++) {
    const int idx = (b * NC + ch) * 512 + d;
    Hpre[idx] = h;                     // h entering chunk ch
    h = fmaf(cA[idx], h, cB[idx]);
  }
}

// ---------------- scan pass 3: apply prefix, write h (8B/lane) ----------
__global__ __launch_bounds__(256) void scan_apply(
    const uint32_t* __restrict__ AC, const float* __restrict__ Hpre,
    float* __restrict__ out) {
  const int blk = blockIdx.x;          // 0..511 = b*NC + ch
  const int d0 = threadIdx.x * 2;
  float2 h = *(const float2*)&Hpre[blk * 512 + d0];
  const size_t base = (size_t)blk * CHUNK * 512 + d0;
#pragma unroll 8
  for (int t = 0; t < CHUNK; t++) {
    const size_t i = base + (size_t)t * 512;
    uint2 v = *(const uint2*)&AC[i];
    f16x2 p0 = __builtin_bit_cast(f16x2, v.x);
    f16x2 p1 = __builtin_bit_cast(f16x2, v.y);
    h.x = fmaf((float)p0[0], h.x, (float)p0[1]);
    h.y = fmaf((float)p1[0], h.y, (float)p1[1]);
    *(float2*)&out[i] = h;
  }
}

// ---------------- launch ----------------
extern "C" void kernel_launch(void* const* d_in, const int* in_sizes, int n_in,
                              void* d_out, int out_size, void* d_ws, size_t ws_size,
                              hipStream_t stream) {
  const float* x  = (const float*)d_in[0];
  const float* Wg = (const float*)d_in[1];
  const float* bg = (const float*)d_in[2];
  const float* Wc = (const float*)d_in[3];
  const float* bc = (const float*)d_in[4];
  float* out = (float*)d_out;

  char* ws = (char*)d_ws;
  // workspace layout (bytes):
  //   [0, 1MB)       wp    f16 packed weights [1024][512]
  //   [1MB, 65MB)    AC    u32 packed (a,b) f16x2 [32768][512]
  //   [65MB..68MB)   cA, cB, Hpre fp32 (1MB each)
  f16*      wp = (f16*)(ws);
  uint32_t* AC = (uint32_t*)(ws + 1048576);
  float*    cA = (float*)(ws + 68157440);
  float*    cB = (float*)(ws + 69206016);
  float*    Hp = (float*)(ws + 70254592);

  prep_w<<<512, 256, 0, stream>>>(Wg, Wc, wp);                       // 1MB pack
  gemm_act<<<(M_ / 128) * 4, 256, 0, stream>>>(x, wp, bg, bc, AC, cA, cB); // 1024 blocks
  scan_chunks<<<32, 64, 0, stream>>>(cA, cB, Hp);
  scan_apply<<<B_ * NC, 256, 0, stream>>>(AC, Hp, out);              // 512 blocks
}

// Round 4
// 206.754 us; speedup vs baseline: 1.0608x; 1.0608x over previous
//
#include <hip/hip_runtime.h>
#include <stdint.h>
#include <stddef.h>

// Problem constants
#define B_ 4
#define L_ 8192
#define D_ 512
#define M_ (B_*L_)      // 32768 rows
#define K_ 512
#define CHUNK 64
#define NC (L_/CHUNK)   // 128 chunks per sequence

typedef _Float16 f16;
typedef f16 f16x2 __attribute__((ext_vector_type(2)));
typedef f16 f16x4 __attribute__((ext_vector_type(4)));
typedef f16 f16x8 __attribute__((ext_vector_type(8)));
typedef float f32x4 __attribute__((ext_vector_type(4)));

// ---------------- async global->LDS (16B/lane) ----------------
__device__ __forceinline__ void async16(const void* g, void* l) {
  __builtin_amdgcn_global_load_lds(
      (const __attribute__((address_space(1))) uint32_t*)g,
      (__attribute__((address_space(3))) uint32_t*)l,
      16, 0, 0);
}

// ---------------- prep: fused cvt_x + pack_w (one dispatch) ----------------
// blocks [0, 16384): convert x fp32 -> f16   (memory-bound, ~16us at ~6 TB/s)
// blocks [16384, 16896): pack Wg ++ Wc into f16 [1024][512]
__global__ __launch_bounds__(256) void prep(const float* __restrict__ x,
                                            const float* __restrict__ Wg,
                                            const float* __restrict__ Wc,
                                            f16* __restrict__ xh,
                                            f16* __restrict__ wp) {
  const int bid = blockIdx.x;
  if (bid < 16384) {
    const int idx = (bid * 256 + threadIdx.x) * 4;
    float4 v = *(const float4*)(x + idx);
    f16x4 o = {(f16)v.x, (f16)v.y, (f16)v.z, (f16)v.w};
    *(f16x4*)(xh + idx) = o;
  } else {
    const int idx = ((bid - 16384) * 256 + threadIdx.x) * 4;  // 0..524287
    const float* src = (idx < 262144) ? (Wg + idx) : (Wc + (idx - 262144));
    float4 v = *(const float4*)src;
    f16x4 o = {(f16)v.x, (f16)v.y, (f16)v.z, (f16)v.w};
    *(f16x4*)(wp + idx) = o;
  }
}

// ---------------- fused dual-B GEMM + activations + chunk composites ------
// v4 = R1's proven all-global_load_lds f16 staging (no reg-stage A: that
// path measured -27us in R2/R3) + the ONLY schedule change: double-buffered
// LDS, STAGE(t+1) issued BEFORE COMPUTE(t), one raw s_barrier + vmcnt(0)
// per K-step (minimum-2-phase recipe). No sched_barrier, no split waits;
// compiler inserts all fine-grained lgkm waits on the ds_read->MFMA path.
__global__ __launch_bounds__(256, 2) void gemm_act(
    const f16* __restrict__ Xh, const f16* __restrict__ Wp,
    const float* __restrict__ bg, const float* __restrict__ bc,
    uint32_t* __restrict__ AC,
    float* __restrict__ cA, float* __restrict__ cB) {
  __shared__ __align__(16) f16 sA[2][128 * 32];
  __shared__ __align__(16) f16 sBg[2][128 * 32];
  __shared__ __align__(16) f16 sBc[2][128 * 32];

  const int tid = threadIdx.x;
  // XCD swizzle: same bm-tile's 4 col-blocks run consecutively on one XCD
  const int id = blockIdx.x;           // 0..1023
  const int xcd = id & 7;
  const int slot = id >> 3;            // 0..127
  const int g_ = xcd * 128 + slot;
  const int bm = g_ >> 2;              // 0..255
  const int bn = g_ & 3;               // 0..3 (128-col tiles)

  const int lane = tid & 63;
  const int w = tid >> 6;
  const int wm = w >> 1, wn = w & 1;   // 2x2 wave grid over 128x128
  const int l15 = lane & 15, quad = lane >> 4;

  // staging: tid -> (row = tid>>2, 16B piece = tid&3); covers 64 rows/round
  const int srow = tid >> 2;
  const int spc8 = (tid & 3) * 8;
  const f16* gA  = Xh + (size_t)(bm * 128 + srow) * K_ + spc8;
  const f16* gBg = Wp + (size_t)(bn * 128 + srow) * K_ + spc8;
  const f16* gBc = Wp + (size_t)(512 + bn * 128 + srow) * K_ + spc8;

  f32x4 accG[4][4] = {};
  f32x4 accC[4][4] = {};

#define STAGE(kk, b) { \
    async16(gA + (kk),  &sA[b][tid * 8]); \
    async16(gA + (size_t)64 * K_ + (kk),  &sA[b][tid * 8 + 64 * 32]); \
    async16(gBg + (kk), &sBg[b][tid * 8]); \
    async16(gBg + (size_t)64 * K_ + (kk), &sBg[b][tid * 8 + 64 * 32]); \
    async16(gBc + (kk), &sBc[b][tid * 8]); \
    async16(gBc + (size_t)64 * K_ + (kk), &sBc[b][tid * 8 + 64 * 32]); }

#define COMPUTE(bC) { \
    f16x8 af[4], bgf[4], bcf[4]; \
    _Pragma("unroll") \
    for (int i = 0; i < 4; i++) \
      af[i] = *(const f16x8*)(&sA[bC][(wm * 64 + i * 16 + l15) * 32 + quad * 8]); \
    _Pragma("unroll") \
    for (int j = 0; j < 4; j++) { \
      bgf[j] = *(const f16x8*)(&sBg[bC][(wn * 64 + j * 16 + l15) * 32 + quad * 8]); \
      bcf[j] = *(const f16x8*)(&sBc[bC][(wn * 64 + j * 16 + l15) * 32 + quad * 8]); \
    } \
    _Pragma("unroll") \
    for (int i = 0; i < 4; i++) \
      _Pragma("unroll") \
      for (int j = 0; j < 4; j++) { \
        accG[i][j] = __builtin_amdgcn_mfma_f32_16x16x32_f16(af[i], bgf[j], accG[i][j], 0, 0, 0); \
        accC[i][j] = __builtin_amdgcn_mfma_f32_16x16x32_f16(af[i], bcf[j], accC[i][j], 0, 0, 0); \
      } }

  // Prologue: stage K-tile 0 into buf 0.
  STAGE(0, 0);
  asm volatile("s_waitcnt vmcnt(0)" ::: "memory");
  __builtin_amdgcn_s_barrier();

  // Steady state: stage t+1 into n while computing t from c.
  // Hazards: reads of buf n (iter t-1) all retired before the t-1 barrier
  // (every ds_read is consumed by an MFMA before it); writes to n (iter t)
  // are after that barrier. One barrier per K-step.
#pragma unroll
  for (int t = 0; t < 15; t++) {
    const int c = t & 1, n = c ^ 1;
    STAGE((t + 1) * 32, n);
    COMPUTE(c);
    asm volatile("s_waitcnt vmcnt(0)" ::: "memory");
    __builtin_amdgcn_s_barrier();
  }
  COMPUTE(1);                          // K-tile 15
#undef COMPUTE
#undef STAGE

  // Epilogue: sigmoid/tanh, pack (a,b) f16x2 -> AC, and per-chunk (P,Q).
  // Wave (wm) owns rows [wm*64, wm*64+64) = exactly chunk c.
  // Within chunk, time index t = i*16 + quad*4 + r (lexicographic i,quad,r).
  const int c = bm * 2 + wm;           // global chunk index 0..511
#pragma unroll
  for (int j = 0; j < 4; j++) {
    const int col = bn * 128 + wn * 64 + j * 16 + l15;   // 0..511
    const float bgv = bg[col];
    const float bcv = bc[col];
    float blkP[4], blkQ[4];
#pragma unroll
    for (int i = 0; i < 4; i++) {
      const int mrow = bm * 128 + wm * 64 + i * 16 + quad * 4;
      float P = 1.0f, Q = 0.0f;
#pragma unroll
      for (int r = 0; r < 4; r++) {
        float yg = accG[i][j][r] + bgv;
        float gg = 1.0f / (1.0f + __expf(-yg));        // sigmoid
        float yc = accC[i][j][r] + bcv;
        yc = fminf(fmaxf(yc, -15.0f), 15.0f);
        float t = __expf(2.0f * yc);
        float cc = (t - 1.0f) / (t + 1.0f);            // tanh
        f16x2 p;
        p[0] = (f16)(1.0f - gg);                        // a
        p[1] = (f16)(gg * cc);                          // b
        *(f16x2*)&AC[(size_t)(mrow + r) * 512 + col] = p;
        // compose with the SAME f16-rounded values scan_apply will read
        const float av = (float)p[0];
        const float bv = (float)p[1];
        Q = fmaf(av, Q, bv);                            // seg over r (t asc)
        P *= av;
      }
      // ordered cross-quad compose: quads 0..3 are consecutive t-segments.
      // comp(first,second) = (Ps*Pf, Ps*Qf + Qs)
      float Pp = __shfl_xor(P, 16);
      float Qp = __shfl_xor(Q, 16);
      float nP = P * Pp;
      float nQ = (quad & 1) ? fmaf(P, Qp, Q) : fmaf(Pp, Q, Qp);
      Pp = __shfl_xor(nP, 32);
      Qp = __shfl_xor(nQ, 32);
      blkP[i] = nP * Pp;
      blkQ[i] = (quad & 2) ? fmaf(nP, Qp, nQ) : fmaf(Pp, nQ, Qp);
    }
    // compose the 4 sixteen-row blocks in t order
    float CP = blkP[0], CQ = blkQ[0];
#pragma unroll
    for (int i = 1; i < 4; i++) {
      CQ = fmaf(blkP[i], CQ, blkQ[i]);
      CP *= blkP[i];
    }
    if (quad == 0) {
      cA[(size_t)c * 512 + col] = CP;
      cB[(size_t)c * 512 + col] = CQ;
    }
  }
}

// ---------------- scan: inline chunk-prefix + apply, 8B/lane ----------------
// Each block = one chunk (b, ch). Thread owns 2 consecutive d columns.
// Prefix over chunks 0..ch-1 from cA/cB (2MB total, L2-resident), then the
// 64-step within-chunk recurrence, writing fp32 h. (Merged version: one
// dispatch, no Hpre round-trip; the O(ch) prefix redo costs less than the
// extra launch, measured R2 vs R3.)
__global__ __launch_bounds__(256) void scan_apply(
    const uint32_t* __restrict__ AC,
    const float* __restrict__ cA, const float* __restrict__ cB,
    float* __restrict__ out) {
  const int blk = blockIdx.x;          // 0..511 = b*NC + ch
  const int ch = blk & (NC - 1);
  const int bseq = blk >> 7;           // NC = 128
  const int d0 = threadIdx.x * 2;

  float h0 = 0.0f, h1 = 0.0f;
  const float* pA = cA + (size_t)(bseq * NC) * 512 + d0;
  const float* pB = cB + (size_t)(bseq * NC) * 512 + d0;
#pragma unroll 4
  for (int cc = 0; cc < ch; cc++) {
    float2 va = *(const float2*)(pA + (size_t)cc * 512);
    float2 vb = *(const float2*)(pB + (size_t)cc * 512);
    h0 = fmaf(va.x, h0, vb.x);
    h1 = fmaf(va.y, h1, vb.y);
  }

  const size_t base = (size_t)blk * CHUNK * 512 + d0;
#pragma unroll 8
  for (int t = 0; t < CHUNK; t++) {
    const size_t i = base + (size_t)t * 512;
    uint2 v = *(const uint2*)&AC[i];
    f16x2 p0 = __builtin_bit_cast(f16x2, v.x);
    f16x2 p1 = __builtin_bit_cast(f16x2, v.y);
    h0 = fmaf((float)p0[0], h0, (float)p0[1]);
    h1 = fmaf((float)p1[0], h1, (float)p1[1]);
    float2 o;
    o.x = h0;
    o.y = h1;
    *(float2*)&out[i] = o;
  }
}

// ---------------- launch ----------------
extern "C" void kernel_launch(void* const* d_in, const int* in_sizes, int n_in,
                              void* d_out, int out_size, void* d_ws, size_t ws_size,
                              hipStream_t stream) {
  const float* x  = (const float*)d_in[0];
  const float* Wg = (const float*)d_in[1];
  const float* bg = (const float*)d_in[2];
  const float* Wc = (const float*)d_in[3];
  const float* bc = (const float*)d_in[4];
  float* out = (float*)d_out;

  char* ws = (char*)d_ws;
  // workspace layout (bytes):
  //   [0, 32MB)      xh   f16 x
  //   [32MB, 33MB)   wp   f16 packed weights [1024][512]
  //   [33MB, 97MB)   AC   u32 packed (a,b) f16x2 [32768][512]
  //   [97MB..99MB)   cA, cB fp32 (1MB each)
  f16*      xh = (f16*)(ws);
  f16*      wp = (f16*)(ws + 33554432);
  uint32_t* AC = (uint32_t*)(ws + 34603008);
  float*    cA = (float*)(ws + 101711872);
  float*    cB = (float*)(ws + 102760448);

  prep<<<16896, 256, 0, stream>>>(x, Wg, Wc, xh, wp);                // cvt + pack
  gemm_act<<<(M_ / 128) * 4, 256, 0, stream>>>(xh, wp, bg, bc, AC, cA, cB); // 1024 blocks
  scan_apply<<<B_ * NC, 256, 0, stream>>>(AC, cA, cB, out);          // 512 blocks
}

// Round 5
// 205.974 us; speedup vs baseline: 1.0648x; 1.0038x over previous
//
#include <hip/hip_runtime.h>
#include <stdint.h>
#include <stddef.h>

// Problem constants
#define B_ 4
#define L_ 8192
#define D_ 512
#define M_ (B_*L_)      // 32768 rows
#define K_ 512
#define CHUNK 64
#define NC (L_/CHUNK)   // 128 chunks per sequence

typedef _Float16 f16;
typedef f16 f16x2 __attribute__((ext_vector_type(2)));
typedef f16 f16x4 __attribute__((ext_vector_type(4)));
typedef f16 f16x8 __attribute__((ext_vector_type(8)));
typedef float f32x4 __attribute__((ext_vector_type(4)));

// ---------------- async global->LDS (16B/lane) ----------------
__device__ __forceinline__ void async16(const void* g, void* l) {
  __builtin_amdgcn_global_load_lds(
      (const __attribute__((address_space(1))) uint32_t*)g,
      (__attribute__((address_space(3))) uint32_t*)l,
      16, 0, 0);
}

// ---------------- prep: fused cvt_x + pack_w (one dispatch) ----------------
// blocks [0, 16384): convert x fp32 -> f16   (memory-bound)
// blocks [16384, 16896): pack Wg ++ Wc into f16 [1024][512]
__global__ __launch_bounds__(256) void prep(const float* __restrict__ x,
                                            const float* __restrict__ Wg,
                                            const float* __restrict__ Wc,
                                            f16* __restrict__ xh,
                                            f16* __restrict__ wp) {
  const int bid = blockIdx.x;
  if (bid < 16384) {
    const int idx = (bid * 256 + threadIdx.x) * 4;
    float4 v = *(const float4*)(x + idx);
    f16x4 o = {(f16)v.x, (f16)v.y, (f16)v.z, (f16)v.w};
    *(f16x4*)(xh + idx) = o;
  } else {
    const int idx = ((bid - 16384) * 256 + threadIdx.x) * 4;  // 0..524287
    const float* src = (idx < 262144) ? (Wg + idx) : (Wc + (idx - 262144));
    float4 v = *(const float4*)src;
    f16x4 o = {(f16)v.x, (f16)v.y, (f16)v.z, (f16)v.w};
    *(f16x4*)(wp + idx) = o;
  }
}

// ---------------- fused dual-B GEMM + activations + chunk composites ------
// v5: 256x128 tile, 512 threads / 8 waves (4m x 2n grid of 64x64 dual
// sub-tiles). Rationale (R1 vs R4 measured identical 69us => staging
// DMA throughput, not latency, is the serializer): per K-step a block now
// stages A 16KB + B 16KB for 2x the output of the old 128x128 tile, so
// per-CU DMA volume/instructions drop 1.5x and Wp re-reads halve.
// Same minimal schedule: double-buffer, STAGE(t+1) before COMPUTE(t),
// one raw s_barrier + vmcnt(0) per K-step.
__global__ __launch_bounds__(512, 2) void gemm_act(
    const f16* __restrict__ Xh, const f16* __restrict__ Wp,
    const float* __restrict__ bg, const float* __restrict__ bc,
    uint32_t* __restrict__ AC,
    float* __restrict__ cA, float* __restrict__ cB) {
  __shared__ __align__(16) f16 sA[2][256 * 32];    // 2 x 16 KB
  __shared__ __align__(16) f16 sBg[2][128 * 32];   // 2 x 8 KB
  __shared__ __align__(16) f16 sBc[2][128 * 32];   // 2 x 8 KB  => 64 KB total

  const int tid = threadIdx.x;
  // XCD swizzle: contiguous bm range per XCD (512 = 8 * 64, bijective)
  const int id = blockIdx.x;           // 0..511
  const int xcd = id & 7;
  const int slot = id >> 3;            // 0..63
  const int g_ = xcd * 64 + slot;
  const int bm = g_ >> 2;              // 0..127 (256-row tiles)
  const int bn = g_ & 3;               // 0..3 (128-col tiles)

  const int lane = tid & 63;
  const int w = tid >> 6;              // 0..7
  const int wm = w >> 1, wn = w & 1;   // 4x2 wave grid over 256x128
  const int l15 = lane & 15, quad = lane >> 4;

  // staging: tid -> (row = tid>>2, 16B piece = tid&3); covers 128 rows/round
  const int srow = tid >> 2;           // 0..127
  const int spc8 = (tid & 3) * 8;
  const f16* gA  = Xh + (size_t)(bm * 256 + srow) * K_ + spc8;
  const f16* gBg = Wp + (size_t)(bn * 128 + srow) * K_ + spc8;
  const f16* gBc = Wp + (size_t)(512 + bn * 128 + srow) * K_ + spc8;

  f32x4 accG[4][4] = {};
  f32x4 accC[4][4] = {};

#define STAGE(kk, b) { \
    async16(gA + (kk),  &sA[b][tid * 8]); \
    async16(gA + (size_t)128 * K_ + (kk), &sA[b][tid * 8 + 128 * 32]); \
    async16(gBg + (kk), &sBg[b][tid * 8]); \
    async16(gBc + (kk), &sBc[b][tid * 8]); }

#define COMPUTE(bC) { \
    f16x8 af[4], bgf[4], bcf[4]; \
    _Pragma("unroll") \
    for (int i = 0; i < 4; i++) \
      af[i] = *(const f16x8*)(&sA[bC][(wm * 64 + i * 16 + l15) * 32 + quad * 8]); \
    _Pragma("unroll") \
    for (int j = 0; j < 4; j++) { \
      bgf[j] = *(const f16x8*)(&sBg[bC][(wn * 64 + j * 16 + l15) * 32 + quad * 8]); \
      bcf[j] = *(const f16x8*)(&sBc[bC][(wn * 64 + j * 16 + l15) * 32 + quad * 8]); \
    } \
    _Pragma("unroll") \
    for (int i = 0; i < 4; i++) \
      _Pragma("unroll") \
      for (int j = 0; j < 4; j++) { \
        accG[i][j] = __builtin_amdgcn_mfma_f32_16x16x32_f16(af[i], bgf[j], accG[i][j], 0, 0, 0); \
        accC[i][j] = __builtin_amdgcn_mfma_f32_16x16x32_f16(af[i], bcf[j], accC[i][j], 0, 0, 0); \
      } }

  // Prologue: stage K-tile 0 into buf 0.
  STAGE(0, 0);
  asm volatile("s_waitcnt vmcnt(0)" ::: "memory");
  __builtin_amdgcn_s_barrier();

  // Steady state: stage t+1 into n while computing t from c.
  // Hazards: reads of buf n (iter t-1) all retired before the t-1 barrier
  // (every ds_read is consumed by an MFMA before it); writes to n (iter t)
  // are after that barrier. One barrier per K-step.
#pragma unroll
  for (int t = 0; t < 15; t++) {
    const int c = t & 1, n = c ^ 1;
    STAGE((t + 1) * 32, n);
    COMPUTE(c);
    asm volatile("s_waitcnt vmcnt(0)" ::: "memory");
    __builtin_amdgcn_s_barrier();
  }
  COMPUTE(1);                          // K-tile 15
#undef COMPUTE
#undef STAGE

  // Epilogue: sigmoid/tanh, pack (a,b) f16x2 -> AC, and per-chunk (P,Q).
  // Wave wm owns rows [wm*64, wm*64+64) of the 256-row tile = chunk
  // c = bm*4 + wm. Within chunk, t = i*16 + quad*4 + r.
  const int c = bm * 4 + wm;           // global chunk index 0..511
#pragma unroll
  for (int j = 0; j < 4; j++) {
    const int col = bn * 128 + wn * 64 + j * 16 + l15;   // 0..511
    const float bgv = bg[col];
    const float bcv = bc[col];
    float blkP[4], blkQ[4];
#pragma unroll
    for (int i = 0; i < 4; i++) {
      const int mrow = bm * 256 + wm * 64 + i * 16 + quad * 4;
      float P = 1.0f, Q = 0.0f;
#pragma unroll
      for (int r = 0; r < 4; r++) {
        float yg = accG[i][j][r] + bgv;
        float gg = 1.0f / (1.0f + __expf(-yg));        // sigmoid
        float yc = accC[i][j][r] + bcv;
        yc = fminf(fmaxf(yc, -15.0f), 15.0f);
        float t = __expf(2.0f * yc);
        float cc = (t - 1.0f) / (t + 1.0f);            // tanh
        f16x2 p;
        p[0] = (f16)(1.0f - gg);                        // a
        p[1] = (f16)(gg * cc);                          // b
        *(f16x2*)&AC[(size_t)(mrow + r) * 512 + col] = p;
        // compose with the SAME f16-rounded values scan_apply will read
        const float av = (float)p[0];
        const float bv = (float)p[1];
        Q = fmaf(av, Q, bv);                            // seg over r (t asc)
        P *= av;
      }
      // ordered cross-quad compose: quads 0..3 are consecutive t-segments.
      // comp(first,second) = (Ps*Pf, Ps*Qf + Qs)
      float Pp = __shfl_xor(P, 16);
      float Qp = __shfl_xor(Q, 16);
      float nP = P * Pp;
      float nQ = (quad & 1) ? fmaf(P, Qp, Q) : fmaf(Pp, Q, Qp);
      Pp = __shfl_xor(nP, 32);
      Qp = __shfl_xor(nQ, 32);
      blkP[i] = nP * Pp;
      blkQ[i] = (quad & 2) ? fmaf(nP, Qp, nQ) : fmaf(Pp, nQ, Qp);
    }
    // compose the 4 sixteen-row blocks in t order
    float CP = blkP[0], CQ = blkQ[0];
#pragma unroll
    for (int i = 1; i < 4; i++) {
      CQ = fmaf(blkP[i], CQ, blkQ[i]);
      CP *= blkP[i];
    }
    if (quad == 0) {
      cA[(size_t)c * 512 + col] = CP;
      cB[(size_t)c * 512 + col] = CQ;
    }
  }
}

// ---------------- scan: inline chunk-prefix + apply, 16B/lane ---------------
// Each block = one chunk (b, ch). Thread owns 4 consecutive d columns
// (uint4/float4 = the peak-BW access width). Prefix over chunks 0..ch-1
// from cA/cB (2MB, L2-resident; fma chain is the only serial part), then
// the 64-step within-chunk recurrence, writing fp32 h.
__global__ __launch_bounds__(128) void scan_apply(
    const uint32_t* __restrict__ AC,
    const float* __restrict__ cA, const float* __restrict__ cB,
    float* __restrict__ out) {
  const int blk = blockIdx.x;          // 0..511 = b*NC + ch
  const int ch = blk & (NC - 1);
  const int bseq = blk >> 7;           // NC = 128
  const int d0 = threadIdx.x * 4;      // 128 thr x 4 cols = 512

  float h0 = 0.0f, h1 = 0.0f, h2 = 0.0f, h3 = 0.0f;
  const float* pA = cA + (size_t)(bseq * NC) * 512 + d0;
  const float* pB = cB + (size_t)(bseq * NC) * 512 + d0;
#pragma unroll 4
  for (int cc = 0; cc < ch; cc++) {
    float4 va = *(const float4*)(pA + (size_t)cc * 512);
    float4 vb = *(const float4*)(pB + (size_t)cc * 512);
    h0 = fmaf(va.x, h0, vb.x);
    h1 = fmaf(va.y, h1, vb.y);
    h2 = fmaf(va.z, h2, vb.z);
    h3 = fmaf(va.w, h3, vb.w);
  }

  const size_t base = (size_t)blk * CHUNK * 512 + d0;
#pragma unroll 8
  for (int t = 0; t < CHUNK; t++) {
    const size_t i = base + (size_t)t * 512;
    uint4 v = *(const uint4*)&AC[i];
    f16x2 p0 = __builtin_bit_cast(f16x2, v.x);
    f16x2 p1 = __builtin_bit_cast(f16x2, v.y);
    f16x2 p2 = __builtin_bit_cast(f16x2, v.z);
    f16x2 p3 = __builtin_bit_cast(f16x2, v.w);
    h0 = fmaf((float)p0[0], h0, (float)p0[1]);
    h1 = fmaf((float)p1[0], h1, (float)p1[1]);
    h2 = fmaf((float)p2[0], h2, (float)p2[1]);
    h3 = fmaf((float)p3[0], h3, (float)p3[1]);
    float4 o;
    o.x = h0; o.y = h1; o.z = h2; o.w = h3;
    *(float4*)&out[i] = o;
  }
}

// ---------------- launch ----------------
extern "C" void kernel_launch(void* const* d_in, const int* in_sizes, int n_in,
                              void* d_out, int out_size, void* d_ws, size_t ws_size,
                              hipStream_t stream) {
  const float* x  = (const float*)d_in[0];
  const float* Wg = (const float*)d_in[1];
  const float* bg = (const float*)d_in[2];
  const float* Wc = (const float*)d_in[3];
  const float* bc = (const float*)d_in[4];
  float* out = (float*)d_out;

  char* ws = (char*)d_ws;
  // workspace layout (bytes):
  //   [0, 32MB)      xh   f16 x
  //   [32MB, 33MB)   wp   f16 packed weights [1024][512]
  //   [33MB, 97MB)   AC   u32 packed (a,b) f16x2 [32768][512]
  //   [97MB..99MB)   cA, cB fp32 (1MB each)
  f16*      xh = (f16*)(ws);
  f16*      wp = (f16*)(ws + 33554432);
  uint32_t* AC = (uint32_t*)(ws + 34603008);
  float*    cA = (float*)(ws + 101711872);
  float*    cB = (float*)(ws + 102760448);

  prep<<<16896, 256, 0, stream>>>(x, Wg, Wc, xh, wp);                // cvt + pack
  gemm_act<<<512, 512, 0, stream>>>(xh, wp, bg, bc, AC, cA, cB);     // 256x128 tiles
  scan_apply<<<B_ * NC, 128, 0, stream>>>(AC, cA, cB, out);          // 512 blocks
}